// Round 1
// 520.881 us; speedup vs baseline: 1.0471x; 1.0471x over previous
//
#include <hip/hip_runtime.h>

#define N_NODES 10000
#define N_EDGES 320000
#define HID 64
#define IN_DIM 32
#define SEQ 168
#define OUT_DIM 10000
#define OF1_COLS 640064           // HID*N_NODES + HID (full row stride of of1_W)
#define NODE_COLS 640000          // node-feature part
#define NODE_NV   160000          // NODE_COLS / 4
#define OF1_SPLITS 64
#define OF1_CHUNK  2500           // NODE_NV / OF1_SPLITS
#define OF1_ROWS   8              // rows per block
#define BUCKET 128                // max degree capacity (mean deg = 32, P(>128) ~ 0)
#define FILLB  1250               // ceil(N_EDGES/256)
#define LIN1B  2500               // N_NODES/4

typedef __attribute__((ext_vector_type(4))) float f32x4;

// ---- K1: bucket-CSR fill  ||  lin1 (unscaled)  ||  weather MLP, one kernel ----
// lin1 no longer reads cursor (dinv moved into the agg loop), so it runs
// concurrently with the atomic fill instead of serializing behind it.
__global__ __launch_bounds__(256) void k_fill_lin1_weather(
        const int* __restrict__ eidx, int* __restrict__ cursor, int* __restrict__ csr,
        const float* __restrict__ x, const float* __restrict__ W1, float* __restrict__ hlin,
        const float* __restrict__ rain, const float* __restrict__ fut,
        const float* __restrict__ w1W, const float* __restrict__ w1b,
        const float* __restrict__ w2W, const float* __restrict__ w2b,
        const float* __restrict__ of1W, float* __restrict__ wtail) {
    int t = threadIdx.x;
    int b = blockIdx.x;
    if (b < FILLB) {
        int e = b * 256 + t;
        if (e < N_EDGES) {
            int s = eidx[e];
            int d = eidx[N_EDGES + e];
            int slot = atomicAdd(&cursor[d], 1);
            csr[d * BUCKET + slot] = s;
        }
    } else if (b < FILLB + LIN1B) {
        __shared__ float Wl[64][33];
        __shared__ float xs[4][32];
        for (int i = t; i < 64 * 32; i += 256) Wl[i >> 5][i & 31] = W1[i];
        int node0 = (b - FILLB) * 4;
        if (t < 128) {
            int n = t >> 5, k = t & 31;
            xs[n][k] = x[(node0 + n) * IN_DIM + k];
        }
        __syncthreads();
        int nl = t >> 6, j = t & 63;
        float acc = 0.f;
#pragma unroll
        for (int k = 0; k < 32; k++) acc += xs[nl][k] * Wl[j][k];
        hlin[(node0 + nl) * HID + j] = acc;      // UNSCALED (dinv applied in agg)
    } else {
        __shared__ float wi[SEQ + 1];
        __shared__ float w1[64];
        __shared__ float wf[64];
        if (t < SEQ) wi[t] = rain[t];
        if (t == SEQ) wi[SEQ] = fut[0];
        __syncthreads();
        if (t < 64) {
            float acc = w1b[t];
            for (int i = 0; i < SEQ + 1; i++) acc += w1W[t * (SEQ + 1) + i] * wi[i];
            w1[t] = fmaxf(acc, 0.f);
        }
        __syncthreads();
        if (t < 64) {
            float acc2 = w2b[t];
#pragma unroll
            for (int i = 0; i < 64; i++) acc2 += w2W[t * 64 + i] * w1[i];
            wf[t] = acc2;
        }
        __syncthreads();
        if (t < 128) {
            const float* Wt = of1W + (size_t)t * OF1_COLS + NODE_COLS;
            float s = 0.f;
#pragma unroll
            for (int w = 0; w < 64; w++) s += Wt[w] * wf[w];
            wtail[t] = s;
        }
    }
}

// ---- K2: GCN aggregation layer-1 + fused lin2.  Wave per node, lane = dim.
// Per-neighbor dinv gathered 64-wide up front, shuffled alongside the index;
// gather loop unrolled 4x so 4 independent L2 loads are in flight per step.
__global__ __launch_bounds__(256) void k_agg1_lin2(
        const float* __restrict__ hlin, const int* __restrict__ cnt,
        const int* __restrict__ csr, const float* __restrict__ b1,
        const float* __restrict__ W2, float* __restrict__ h2) {
    __shared__ float Wl[64][65];
    __shared__ float xs[4][64];
    int t = threadIdx.x;
    for (int i = t; i < 64 * 64; i += 256) Wl[i >> 6][i & 63] = W2[i];
    int wid = t >> 6, lane = t & 63;
    int n = blockIdx.x * 4 + wid;
    int deg = cnt[n];
    float dn = rsqrtf((float)(deg + 1));
    float acc = hlin[n * HID + lane] * dn;       // self-loop: dinv[n]*h[n]
    const int* row = csr + n * BUCKET;
    for (int base = 0; base < deg; base += 64) {
        int idx = base + lane;
        int sv = row[(idx < deg) ? idx : 0];     // coalesced 64-wide index load
        float dv = (idx < deg) ? rsqrtf((float)(cnt[sv] + 1)) : 0.f;
        int m = deg - base;
        if (m > 64) m = 64;
        int m4 = (m + 3) & ~3;                   // pad to x4; padded slots have dv=0
        for (int j = 0; j < m4; j += 4) {
            int s0 = __shfl(sv, j, 64), s1 = __shfl(sv, j + 1, 64);
            int s2 = __shfl(sv, j + 2, 64), s3 = __shfl(sv, j + 3, 64);
            float d0 = __shfl(dv, j, 64), d1 = __shfl(dv, j + 1, 64);
            float d2 = __shfl(dv, j + 2, 64), d3 = __shfl(dv, j + 3, 64);
            float v0 = hlin[s0 * HID + lane];
            float v1 = hlin[s1 * HID + lane];
            float v2 = hlin[s2 * HID + lane];
            float v3 = hlin[s3 * HID + lane];
            acc = fmaf(d0, v0, acc);
            acc = fmaf(d1, v1, acc);
            acc = fmaf(d2, v2, acc);
            acc = fmaf(d3, v3, acc);
        }
    }
    float v = fmaxf(dn * acc + b1[lane], 0.f);   // h1[n][lane]
    xs[wid][lane] = v;
    __syncthreads();                             // covers Wl staging + xs publish
    float a2 = 0.f;
#pragma unroll
    for (int k = 0; k < 64; k++) a2 += xs[wid][k] * Wl[lane][k];
    h2[n * HID + lane] = a2;                     // UNSCALED lin2 output
}

// ---- K3: GCN aggregation layer-2 (+bias, relu, clip) -> comb ----
__global__ __launch_bounds__(256) void k_agg2(
        const float* __restrict__ h2, const int* __restrict__ cnt,
        const int* __restrict__ csr, const float* __restrict__ b2,
        float* __restrict__ comb) {
    int t = threadIdx.x;
    int wid = t >> 6, lane = t & 63;
    int n = blockIdx.x * 4 + wid;
    int deg = cnt[n];
    float dn = rsqrtf((float)(deg + 1));
    float acc = h2[n * HID + lane] * dn;
    const int* row = csr + n * BUCKET;
    for (int base = 0; base < deg; base += 64) {
        int idx = base + lane;
        int sv = row[(idx < deg) ? idx : 0];
        float dv = (idx < deg) ? rsqrtf((float)(cnt[sv] + 1)) : 0.f;
        int m = deg - base;
        if (m > 64) m = 64;
        int m4 = (m + 3) & ~3;
        for (int j = 0; j < m4; j += 4) {
            int s0 = __shfl(sv, j, 64), s1 = __shfl(sv, j + 1, 64);
            int s2 = __shfl(sv, j + 2, 64), s3 = __shfl(sv, j + 3, 64);
            float d0 = __shfl(dv, j, 64), d1 = __shfl(dv, j + 1, 64);
            float d2 = __shfl(dv, j + 2, 64), d3 = __shfl(dv, j + 3, 64);
            float v0 = h2[s0 * HID + lane];
            float v1 = h2[s1 * HID + lane];
            float v2 = h2[s2 * HID + lane];
            float v3 = h2[s3 * HID + lane];
            acc = fmaf(d0, v0, acc);
            acc = fmaf(d1, v1, acc);
            acc = fmaf(d2, v2, acc);
            acc = fmaf(d3, v3, acc);
        }
    }
    float v = dn * acc + b2[lane];
    v = fmaxf(v, 0.f);
    v = fminf(v, 10.f);
    comb[n * HID + lane] = v;
}

// ---- of1 matvec over node cols: 8 rows per block, 64 column-splits ----
__global__ __launch_bounds__(256) void k_of1(const float* __restrict__ W, const float* __restrict__ comb,
                                             float* __restrict__ o_pre) {
    int split = blockIdx.x;              // 0..63
    int j0 = blockIdx.y * OF1_ROWS;      // 0..120
    int i0 = split * OF1_CHUNK;
    int i1 = i0 + OF1_CHUNK;
    const f32x4* C4 = (const f32x4*)comb;
    const f32x4* Wr[OF1_ROWS];
#pragma unroll
    for (int r = 0; r < OF1_ROWS; r++)
        Wr[r] = (const f32x4*)(W + (size_t)(j0 + r) * OF1_COLS);
    float a[OF1_ROWS];
#pragma unroll
    for (int r = 0; r < OF1_ROWS; r++) a[r] = 0.f;
    for (int i = i0 + threadIdx.x; i < i1; i += 256) {
        f32x4 cv = C4[i];
#pragma unroll
        for (int r = 0; r < OF1_ROWS; r++) {
            f32x4 wv = __builtin_nontemporal_load(&Wr[r][i]);
            a[r] += wv.x * cv.x + wv.y * cv.y + wv.z * cv.z + wv.w * cv.w;
        }
    }
#pragma unroll
    for (int off = 1; off < 64; off <<= 1) {
#pragma unroll
        for (int r = 0; r < OF1_ROWS; r++) a[r] += __shfl_xor(a[r], off, 64);
    }
    __shared__ float red[4][OF1_ROWS];
    int lane = threadIdx.x & 63, wid = threadIdx.x >> 6;
    if (lane == 0) {
#pragma unroll
        for (int r = 0; r < OF1_ROWS; r++) red[wid][r] = a[r];
    }
    __syncthreads();
    if (threadIdx.x < OF1_ROWS)
        atomicAdd(&o_pre[j0 + threadIdx.x],
                  red[0][threadIdx.x] + red[1][threadIdx.x] + red[2][threadIdx.x] + red[3][threadIdx.x]);
}

// ---- of2 matvec with fused relu(o_pre + of1_b + wtail) ----
__global__ __launch_bounds__(256) void k_of2(const float* __restrict__ W, const float* __restrict__ of2b,
                                             const float* __restrict__ o_pre, const float* __restrict__ of1b,
                                             const float* __restrict__ wtail, float* __restrict__ out) {
    __shared__ float os[128];
    int t = threadIdx.x;
    if (t < 128) os[t] = fmaxf(o_pre[t] + of1b[t] + wtail[t], 0.f);
    __syncthreads();
    int k = blockIdx.x * 256 + t;
    if (k >= OUT_DIM) return;
    const f32x4* Wr = (const f32x4*)(W + (size_t)k * 128);
    float acc = of2b[k];
#pragma unroll
    for (int i = 0; i < 32; i++) {
        f32x4 wv = __builtin_nontemporal_load(&Wr[i]);
        int base = i * 4;
        acc += wv.x * os[base + 0] + wv.y * os[base + 1] + wv.z * os[base + 2] + wv.w * os[base + 3];
    }
    out[k] = acc;
}

extern "C" void kernel_launch(void* const* d_in, const int* in_sizes, int n_in,
                              void* d_out, int out_size, void* d_ws, size_t ws_size,
                              hipStream_t stream) {
    const float* x    = (const float*)d_in[0];
    const int*  eidx  = (const int*)d_in[1];
    const float* rain = (const float*)d_in[2];
    const float* fut  = (const float*)d_in[3];
    const float* W1   = (const float*)d_in[4];
    const float* b1   = (const float*)d_in[5];
    const float* W2   = (const float*)d_in[6];
    const float* b2   = (const float*)d_in[7];
    const float* wf1W = (const float*)d_in[8];
    const float* wf1b = (const float*)d_in[9];
    const float* wf2W = (const float*)d_in[10];
    const float* wf2b = (const float*)d_in[11];
    const float* of1W = (const float*)d_in[12];
    const float* of1b = (const float*)d_in[13];
    const float* of2W = (const float*)d_in[14];
    const float* of2b = (const float*)d_in[15];
    float* out = (float*)d_out;

    char* p = (char*)d_ws;
    // zero region: [cursor | o_pre] contiguous -> one memset of 40512 B
    int*   cursor = (int*)(p + 0);            // 10000 ints (= degree after fill)
    float* o_pre  = (float*)(p + 40000);      // 128 f32   (ends 40512)
    int*   csr    = (int*)(p + 40960);        // 10000*128 ints = 5.12 MB (ends 5160960)
    float* hlin   = (float*)(p + 5242880);    // 10000*64 f32 (lin1 out, unscaled)
    float* h2     = (float*)(p + 7864320);    // 10000*64 f32 (lin2 out, unscaled)
    float* comb   = (float*)(p + 10485760);   // 640000 f32 (node features)
    float* wtail  = (float*)(p + 13107200);   // 128 f32

    hipMemsetAsync(p, 0, 40512, stream);

    k_fill_lin1_weather<<<FILLB + LIN1B + 1, 256, 0, stream>>>(
        eidx, cursor, csr, x, W1, hlin, rain, fut, wf1W, wf1b, wf2W, wf2b, of1W, wtail);

    k_agg1_lin2<<<N_NODES / 4, 256, 0, stream>>>(hlin, cursor, csr, b1, W2, h2);
    k_agg2<<<N_NODES / 4, 256, 0, stream>>>(h2, cursor, csr, b2, comb);

    k_of1<<<dim3(OF1_SPLITS, 128 / OF1_ROWS), 256, 0, stream>>>(of1W, comb, o_pre);
    k_of2<<<(OUT_DIM + 255) / 256, 256, 0, stream>>>(of2W, of2b, o_pre, of1b, wtail, out);
}

// Round 3
// 510.532 us; speedup vs baseline: 1.0683x; 1.0203x over previous
//
#include <hip/hip_runtime.h>

#define N_NODES 10000
#define N_EDGES 320000
#define HID 64
#define IN_DIM 32
#define SEQ 168
#define OUT_DIM 10000
#define OF1_COLS 640064           // HID*N_NODES + HID (full row stride of of1_W)
#define NODE_COLS 640000          // node-feature part
#define BUCKET 128                // max degree capacity (mean deg = 32, P(>128) ~ 0)
#define FILLB  1250               // ceil(N_EDGES/256)
#define LIN1B  2500               // N_NODES/4
#define NSLOT  64                 // o_pre accumulation slots (atomic spread)

typedef __attribute__((ext_vector_type(4))) float f32x4;

// ---- K1: bucket-CSR fill  ||  lin1 (unscaled)  ||  weather MLP, one kernel ----
__global__ __launch_bounds__(256) void k_fill_lin1_weather(
        const int* __restrict__ eidx, int* __restrict__ cursor, int* __restrict__ csr,
        const float* __restrict__ x, const float* __restrict__ W1, float* __restrict__ hlin,
        const float* __restrict__ rain, const float* __restrict__ fut,
        const float* __restrict__ w1W, const float* __restrict__ w1b,
        const float* __restrict__ w2W, const float* __restrict__ w2b,
        const float* __restrict__ of1W, float* __restrict__ wtail) {
    int t = threadIdx.x;
    int b = blockIdx.x;
    if (b < FILLB) {
        int e = b * 256 + t;
        if (e < N_EDGES) {
            int s = eidx[e];
            int d = eidx[N_EDGES + e];
            int slot = atomicAdd(&cursor[d], 1);
            csr[d * BUCKET + slot] = s;
        }
    } else if (b < FILLB + LIN1B) {
        __shared__ float Wl[64][33];
        __shared__ float xs[4][32];
        for (int i = t; i < 64 * 32; i += 256) Wl[i >> 5][i & 31] = W1[i];
        int node0 = (b - FILLB) * 4;
        if (t < 128) {
            int n = t >> 5, k = t & 31;
            xs[n][k] = x[(node0 + n) * IN_DIM + k];
        }
        __syncthreads();
        int nl = t >> 6, j = t & 63;
        float acc = 0.f;
#pragma unroll
        for (int k = 0; k < 32; k++) acc += xs[nl][k] * Wl[j][k];
        hlin[(node0 + nl) * HID + j] = acc;      // UNSCALED (dinv applied in agg)
    } else {
        __shared__ float wi[SEQ + 1];
        __shared__ float w1[64];
        __shared__ float wf[64];
        if (t < SEQ) wi[t] = rain[t];
        if (t == SEQ) wi[SEQ] = fut[0];
        __syncthreads();
        if (t < 64) {
            float acc = w1b[t];
            for (int i = 0; i < SEQ + 1; i++) acc += w1W[t * (SEQ + 1) + i] * wi[i];
            w1[t] = fmaxf(acc, 0.f);
        }
        __syncthreads();
        if (t < 64) {
            float acc2 = w2b[t];
#pragma unroll
            for (int i = 0; i < 64; i++) acc2 += w2W[t * 64 + i] * w1[i];
            wf[t] = acc2;
        }
        __syncthreads();
        if (t < 128) {
            const float* Wt = of1W + (size_t)t * OF1_COLS + NODE_COLS;
            float s = 0.f;
#pragma unroll
            for (int w = 0; w < 64; w++) s += Wt[w] * wf[w];
            wtail[t] = s;
        }
    }
}

// ---- K2: GCN aggregation layer-1 + fused lin2.  Wave per node, lane = dim. ----
__global__ __launch_bounds__(256) void k_agg1_lin2(
        const float* __restrict__ hlin, const int* __restrict__ cnt,
        const int* __restrict__ csr, const float* __restrict__ b1,
        const float* __restrict__ W2, float* __restrict__ h2) {
    __shared__ float Wl[64][65];
    __shared__ float xs[4][64];
    int t = threadIdx.x;
    for (int i = t; i < 64 * 64; i += 256) Wl[i >> 6][i & 63] = W2[i];
    int wid = t >> 6, lane = t & 63;
    int n = blockIdx.x * 4 + wid;
    int deg = cnt[n];
    float dn = rsqrtf((float)(deg + 1));
    float acc = hlin[n * HID + lane] * dn;       // self-loop: dinv[n]*h[n]
    const int* row = csr + n * BUCKET;
    for (int base = 0; base < deg; base += 64) {
        int idx = base + lane;
        int sv = row[(idx < deg) ? idx : 0];     // coalesced 64-wide index load
        float dv = (idx < deg) ? rsqrtf((float)(cnt[sv] + 1)) : 0.f;
        int m = deg - base;
        if (m > 64) m = 64;
        int m4 = (m + 3) & ~3;                   // pad to x4; padded slots have dv=0
        for (int j = 0; j < m4; j += 4) {
            int s0 = __shfl(sv, j, 64), s1 = __shfl(sv, j + 1, 64);
            int s2 = __shfl(sv, j + 2, 64), s3 = __shfl(sv, j + 3, 64);
            float d0 = __shfl(dv, j, 64), d1 = __shfl(dv, j + 1, 64);
            float d2 = __shfl(dv, j + 2, 64), d3 = __shfl(dv, j + 3, 64);
            float v0 = hlin[s0 * HID + lane];
            float v1 = hlin[s1 * HID + lane];
            float v2 = hlin[s2 * HID + lane];
            float v3 = hlin[s3 * HID + lane];
            acc = fmaf(d0, v0, acc);
            acc = fmaf(d1, v1, acc);
            acc = fmaf(d2, v2, acc);
            acc = fmaf(d3, v3, acc);
        }
    }
    float v = fmaxf(dn * acc + b1[lane], 0.f);   // h1[n][lane]
    xs[wid][lane] = v;
    __syncthreads();                             // covers Wl staging + xs publish
    float a2 = 0.f;
#pragma unroll
    for (int k = 0; k < 64; k++) a2 += xs[wid][k] * Wl[lane][k];
    h2[n * HID + lane] = a2;                     // UNSCALED lin2 output
}

// ---- K3: agg layer-2 fused with of1 column panel.
// Phase A: wave per node computes comb[4][64] into LDS (gather, latency-bound).
// Phase B: block streams of1_W[128 rows x 256 cols] (128 KB, nontemporal) and
//          dot-reduces against LDS comb; partials atomicAdd into o_pre slots.
// NOTE: all __shfl_xor hoisted OUT of conditional expressions — a shfl inside a
// ternary branch may execute with partial exec and pull from inactive lanes.
__global__ __launch_bounds__(256) void k_agg2_of1(
        const float* __restrict__ h2, const int* __restrict__ cnt,
        const int* __restrict__ csr, const float* __restrict__ b2,
        const float* __restrict__ of1W, float* __restrict__ o_pre) {
    __shared__ float xs[4][64];                  // comb values for 4 nodes
    int t = threadIdx.x;
    int wid = t >> 6, lane = t & 63;
    int n = blockIdx.x * 4 + wid;
    int deg = cnt[n];
    float dn = rsqrtf((float)(deg + 1));
    float acc = h2[n * HID + lane] * dn;
    const int* row = csr + n * BUCKET;
    for (int base = 0; base < deg; base += 64) {
        int idx = base + lane;
        int sv = row[(idx < deg) ? idx : 0];
        float dv = (idx < deg) ? rsqrtf((float)(cnt[sv] + 1)) : 0.f;
        int m = deg - base;
        if (m > 64) m = 64;
        int m4 = (m + 3) & ~3;
        for (int j = 0; j < m4; j += 4) {
            int s0 = __shfl(sv, j, 64), s1 = __shfl(sv, j + 1, 64);
            int s2 = __shfl(sv, j + 2, 64), s3 = __shfl(sv, j + 3, 64);
            float d0 = __shfl(dv, j, 64), d1 = __shfl(dv, j + 1, 64);
            float d2 = __shfl(dv, j + 2, 64), d3 = __shfl(dv, j + 3, 64);
            float v0 = h2[s0 * HID + lane];
            float v1 = h2[s1 * HID + lane];
            float v2 = h2[s2 * HID + lane];
            float v3 = h2[s3 * HID + lane];
            acc = fmaf(d0, v0, acc);
            acc = fmaf(d1, v1, acc);
            acc = fmaf(d2, v2, acc);
            acc = fmaf(d3, v3, acc);
        }
    }
    float v = dn * acc + b2[lane];
    v = fmaxf(v, 0.f);
    v = fminf(v, 10.f);
    xs[wid][lane] = v;                           // comb never hits global
    __syncthreads();

    // ---- Phase B: of1 panel.  Wave wid owns rows [wid*32, wid*32+32). ----
    f32x4 c = ((const f32x4*)xs)[lane];          // lane's 4 comb values (hoisted)
    size_t colbase = (size_t)blockIdx.x * 256;   // = n0 * HID
    float* oslot = o_pre + (size_t)(blockIdx.x & (NSLOT - 1)) * 128;
    int j0w = wid * 32;
#pragma unroll 2
    for (int g = 0; g < 8; g++) {
        int j0 = j0w + g * 4;
        const f32x4* W0 = (const f32x4*)(of1W + (size_t)(j0 + 0) * OF1_COLS + colbase);
        const f32x4* W1r = (const f32x4*)(of1W + (size_t)(j0 + 1) * OF1_COLS + colbase);
        const f32x4* W2r = (const f32x4*)(of1W + (size_t)(j0 + 2) * OF1_COLS + colbase);
        const f32x4* W3r = (const f32x4*)(of1W + (size_t)(j0 + 3) * OF1_COLS + colbase);
        f32x4 w0 = __builtin_nontemporal_load(&W0[lane]);
        f32x4 w1 = __builtin_nontemporal_load(&W1r[lane]);
        f32x4 w2 = __builtin_nontemporal_load(&W2r[lane]);
        f32x4 w3 = __builtin_nontemporal_load(&W3r[lane]);
        float a0 = w0.x * c.x + w0.y * c.y + w0.z * c.z + w0.w * c.w;
        float a1 = w1.x * c.x + w1.y * c.y + w1.z * c.z + w1.w * c.w;
        float a2 = w2.x * c.x + w2.y * c.y + w2.z * c.z + w2.w * c.w;
        float a3 = w3.x * c.x + w3.y * c.y + w3.z * c.z + w3.w * c.w;
        // ---- packed butterfly, shfls unconditional, selects on registers ----
        float a0s = a0 + __shfl_xor(a0, 32, 64);
        float a1s = a1 + __shfl_xor(a1, 32, 64);
        float a2s = a2 + __shfl_xor(a2, 32, 64);
        float a3s = a3 + __shfl_xor(a3, 32, 64);
        float c01 = (lane < 32) ? a0s : a1s;     // lanes 0-31: a0 halves, 32-63: a1
        float c23 = (lane < 32) ? a2s : a3s;
        float c01b = c01 + __shfl_xor(c01, 16, 64);
        float c23b = c23 + __shfl_xor(c23, 16, 64);
        float e = ((lane & 16) == 0) ? c01b : c23b;
        e += __shfl_xor(e, 8, 64);
        e += __shfl_xor(e, 4, 64);
        e += __shfl_xor(e, 2, 64);
        e += __shfl_xor(e, 1, 64);
        // lane 0 -> j0+0, lane 16 -> j0+2, lane 32 -> j0+1, lane 48 -> j0+3
        if ((lane & 15) == 0) {
            int roff = ((lane & 16) ? 2 : 0) + ((lane & 32) ? 1 : 0);
            atomicAdd(&oslot[j0 + roff], e);
        }
    }
}

// ---- of2 matvec with fused slot-reduce + relu(o_pre + of1_b + wtail) ----
__global__ __launch_bounds__(256) void k_of2(const float* __restrict__ W, const float* __restrict__ of2b,
                                             const float* __restrict__ o_pre, const float* __restrict__ of1b,
                                             const float* __restrict__ wtail, float* __restrict__ out) {
    __shared__ float os[128];
    int t = threadIdx.x;
    if (t < 128) {
        float s = of1b[t] + wtail[t];
#pragma unroll
        for (int cidx = 0; cidx < NSLOT; cidx++) s += o_pre[cidx * 128 + t];
        os[t] = fmaxf(s, 0.f);
    }
    __syncthreads();
    int k = blockIdx.x * 256 + t;
    if (k >= OUT_DIM) return;
    const f32x4* Wr = (const f32x4*)(W + (size_t)k * 128);
    float acc = of2b[k];
#pragma unroll
    for (int i = 0; i < 32; i++) {
        f32x4 wv = __builtin_nontemporal_load(&Wr[i]);
        int base = i * 4;
        acc += wv.x * os[base + 0] + wv.y * os[base + 1] + wv.z * os[base + 2] + wv.w * os[base + 3];
    }
    out[k] = acc;
}

extern "C" void kernel_launch(void* const* d_in, const int* in_sizes, int n_in,
                              void* d_out, int out_size, void* d_ws, size_t ws_size,
                              hipStream_t stream) {
    const float* x    = (const float*)d_in[0];
    const int*  eidx  = (const int*)d_in[1];
    const float* rain = (const float*)d_in[2];
    const float* fut  = (const float*)d_in[3];
    const float* W1   = (const float*)d_in[4];
    const float* b1   = (const float*)d_in[5];
    const float* W2   = (const float*)d_in[6];
    const float* b2   = (const float*)d_in[7];
    const float* wf1W = (const float*)d_in[8];
    const float* wf1b = (const float*)d_in[9];
    const float* wf2W = (const float*)d_in[10];
    const float* wf2b = (const float*)d_in[11];
    const float* of1W = (const float*)d_in[12];
    const float* of1b = (const float*)d_in[13];
    const float* of2W = (const float*)d_in[14];
    const float* of2b = (const float*)d_in[15];
    float* out = (float*)d_out;

    char* p = (char*)d_ws;
    // zero region: [cursor | o_pre(64 slots x 128)] contiguous -> one memset of 72768 B
    int*   cursor = (int*)(p + 0);            // 10000 ints (= degree after fill)
    float* o_pre  = (float*)(p + 40000);      // 64*128 f32 = 32768 B (ends 72768)
    int*   csr    = (int*)(p + 73728);        // 10000*128 ints = 5.12 MB (ends 5193728)
    float* hlin   = (float*)(p + 5242880);    // 10000*64 f32 (lin1 out, unscaled)
    float* h2     = (float*)(p + 7864320);    // 10000*64 f32 (lin2 out, unscaled)
    float* wtail  = (float*)(p + 10485760);   // 128 f32

    hipMemsetAsync(p, 0, 72768, stream);

    k_fill_lin1_weather<<<FILLB + LIN1B + 1, 256, 0, stream>>>(
        eidx, cursor, csr, x, W1, hlin, rain, fut, wf1W, wf1b, wf2W, wf2b, of1W, wtail);

    k_agg1_lin2<<<N_NODES / 4, 256, 0, stream>>>(hlin, cursor, csr, b1, W2, h2);
    k_agg2_of1<<<N_NODES / 4, 256, 0, stream>>>(h2, cursor, csr, b2, of1W, o_pre);

    k_of2<<<(OUT_DIM + 255) / 256, 256, 0, stream>>>(of2W, of2b, o_pre, of1b, wtail, out);
}

// Round 4
// 509.265 us; speedup vs baseline: 1.0710x; 1.0025x over previous
//
#include <hip/hip_runtime.h>

#define N_NODES 10000
#define N_EDGES 320000
#define HID 64
#define IN_DIM 32
#define SEQ 168
#define OUT_DIM 10000
#define OF1_COLS 640064           // HID*N_NODES + HID (full row stride of of1_W)
#define NODE_COLS 640000          // node-feature part
#define BUCKET 128                // max degree capacity (mean deg = 32, P(>128) ~ 0)
#define FILLB  1250               // ceil(N_EDGES/256)
#define LIN1B  2500               // N_NODES/4
#define NSLOT  64                 // o_pre accumulation slots (atomic spread)

typedef __attribute__((ext_vector_type(4))) float f32x4;

// ---- K1: bucket-CSR fill  ||  lin1 (unscaled)  ||  weather MLP, one kernel ----
__global__ __launch_bounds__(256) void k_fill_lin1_weather(
        const int* __restrict__ eidx, int* __restrict__ cursor, int* __restrict__ csr,
        const float* __restrict__ x, const float* __restrict__ W1, float* __restrict__ hlin,
        const float* __restrict__ rain, const float* __restrict__ fut,
        const float* __restrict__ w1W, const float* __restrict__ w1b,
        const float* __restrict__ w2W, const float* __restrict__ w2b,
        const float* __restrict__ of1W, float* __restrict__ wtail) {
    int t = threadIdx.x;
    int b = blockIdx.x;
    if (b < FILLB) {
        int e = b * 256 + t;
        if (e < N_EDGES) {
            int s = eidx[e];
            int d = eidx[N_EDGES + e];
            int slot = atomicAdd(&cursor[d], 1);
            csr[d * BUCKET + slot] = s;
        }
    } else if (b < FILLB + LIN1B) {
        __shared__ float Wl[64][33];
        __shared__ float xs[4][32];
        for (int i = t; i < 64 * 32; i += 256) Wl[i >> 5][i & 31] = W1[i];
        int node0 = (b - FILLB) * 4;
        if (t < 128) {
            int n = t >> 5, k = t & 31;
            xs[n][k] = x[(node0 + n) * IN_DIM + k];
        }
        __syncthreads();
        int nl = t >> 6, j = t & 63;
        float acc = 0.f;
#pragma unroll
        for (int k = 0; k < 32; k++) acc += xs[nl][k] * Wl[j][k];
        hlin[(node0 + nl) * HID + j] = acc;      // UNSCALED (dinv applied in agg1)
    } else {
        __shared__ float wi[SEQ + 1];
        __shared__ float w1[64];
        __shared__ float wf[64];
        if (t < SEQ) wi[t] = rain[t];
        if (t == SEQ) wi[SEQ] = fut[0];
        __syncthreads();
        if (t < 64) {
            float acc = w1b[t];
            for (int i = 0; i < SEQ + 1; i++) acc += w1W[t * (SEQ + 1) + i] * wi[i];
            w1[t] = fmaxf(acc, 0.f);
        }
        __syncthreads();
        if (t < 64) {
            float acc2 = w2b[t];
#pragma unroll
            for (int i = 0; i < 64; i++) acc2 += w2W[t * 64 + i] * w1[i];
            wf[t] = acc2;
        }
        __syncthreads();
        if (t < 128) {
            const float* Wt = of1W + (size_t)t * OF1_COLS + NODE_COLS;
            float s = 0.f;
#pragma unroll
            for (int w = 0; w < 64; w++) s += Wt[w] * wf[w];
            wtail[t] = s;
        }
    }
}

// ---- K2: GCN aggregation layer-1 + fused lin2.  Wave per node, lane = dim.
// Epilogue writes h2 PRE-SCALED by dinv[n] so agg2's gather needs no dv at all.
__global__ __launch_bounds__(256) void k_agg1_lin2(
        const float* __restrict__ hlin, const int* __restrict__ cnt,
        const int* __restrict__ csr, const float* __restrict__ b1,
        const float* __restrict__ W2, float* __restrict__ h2) {
    __shared__ float Wl[64][65];
    __shared__ float xs[4][64];
    int t = threadIdx.x;
    for (int i = t; i < 64 * 64; i += 256) Wl[i >> 6][i & 63] = W2[i];
    int wid = t >> 6, lane = t & 63;
    int n = blockIdx.x * 4 + wid;
    int deg = cnt[n];
    float dn = rsqrtf((float)(deg + 1));
    float acc = hlin[n * HID + lane] * dn;       // self-loop: dinv[n]*h[n]
    const int* row = csr + n * BUCKET;
    for (int base = 0; base < deg; base += 64) {
        int idx = base + lane;
        int sv = row[(idx < deg) ? idx : 0];     // coalesced 64-wide index load
        float dv = (idx < deg) ? rsqrtf((float)(cnt[sv] + 1)) : 0.f;
        int m = deg - base;
        if (m > 64) m = 64;
        int m4 = (m + 3) & ~3;                   // pad to x4; padded slots have dv=0
        for (int j = 0; j < m4; j += 4) {
            int s0 = __shfl(sv, j, 64), s1 = __shfl(sv, j + 1, 64);
            int s2 = __shfl(sv, j + 2, 64), s3 = __shfl(sv, j + 3, 64);
            float d0 = __shfl(dv, j, 64), d1 = __shfl(dv, j + 1, 64);
            float d2 = __shfl(dv, j + 2, 64), d3 = __shfl(dv, j + 3, 64);
            float v0 = hlin[s0 * HID + lane];
            float v1 = hlin[s1 * HID + lane];
            float v2 = hlin[s2 * HID + lane];
            float v3 = hlin[s3 * HID + lane];
            acc = fmaf(d0, v0, acc);
            acc = fmaf(d1, v1, acc);
            acc = fmaf(d2, v2, acc);
            acc = fmaf(d3, v3, acc);
        }
    }
    float v = fmaxf(dn * acc + b1[lane], 0.f);   // h1[n][lane]
    xs[wid][lane] = v;
    __syncthreads();                             // covers Wl staging + xs publish
    float a2 = 0.f;
#pragma unroll
    for (int k = 0; k < 64; k++) a2 += xs[wid][k] * Wl[lane][k];
    h2[n * HID + lane] = a2 * dn;                // PRE-SCALED lin2 output (dinv[n]*...)
}

// ---- K3: agg layer-2 fused with of1 column panel.
// Phase A: wave per node computes comb[4][64] into LDS (pure-add gather, h2 pre-scaled).
// Phase B: block streams of1_W[128 rows x 256 cols] (nontemporal), 2-stage
//          register pipeline; group-0 loads issued BEFORE phase A so HBM latency
//          hides under the gather.
__global__ __launch_bounds__(256) void k_agg2_of1(
        const float* __restrict__ h2, const int* __restrict__ cnt,
        const int* __restrict__ csr, const float* __restrict__ b2,
        const float* __restrict__ of1W, float* __restrict__ o_pre) {
    __shared__ float xs[4][64];                  // comb values for 4 nodes
    int t = threadIdx.x;
    int wid = t >> 6, lane = t & 63;
    size_t colbase = (size_t)blockIdx.x * 256;   // = n0 * HID
    int j0w = wid * 32;

#define LOADG(buf, g) do {                                                                  \
        int j0_ = j0w + (g) * 4;                                                            \
        buf[0] = __builtin_nontemporal_load((const f32x4*)(of1W + (size_t)(j0_ + 0) * OF1_COLS + colbase) + lane); \
        buf[1] = __builtin_nontemporal_load((const f32x4*)(of1W + (size_t)(j0_ + 1) * OF1_COLS + colbase) + lane); \
        buf[2] = __builtin_nontemporal_load((const f32x4*)(of1W + (size_t)(j0_ + 2) * OF1_COLS + colbase) + lane); \
        buf[3] = __builtin_nontemporal_load((const f32x4*)(of1W + (size_t)(j0_ + 3) * OF1_COLS + colbase) + lane); \
    } while (0)

    f32x4 bufA[4], bufB[4];
    LOADG(bufA, 0);                              // in flight during the entire gather

    // ---- Phase A ----
    int n = blockIdx.x * 4 + wid;
    int deg = cnt[n];
    float dn = rsqrtf((float)(deg + 1));
    float acc = h2[n * HID + lane];              // self-loop (pre-scaled)
    const int* row = csr + n * BUCKET;
    for (int base = 0; base < deg; base += 64) {
        int idx = base + lane;
        int sv = row[(idx < deg) ? idx : 0];
        int m = deg - base;
        if (m > 64) m = 64;
        int mfull = m & ~3;
        for (int j = 0; j < mfull; j += 4) {
            int s0 = __shfl(sv, j, 64), s1 = __shfl(sv, j + 1, 64);
            int s2 = __shfl(sv, j + 2, 64), s3 = __shfl(sv, j + 3, 64);
            float v0 = h2[s0 * HID + lane];
            float v1 = h2[s1 * HID + lane];
            float v2 = h2[s2 * HID + lane];
            float v3 = h2[s3 * HID + lane];
            acc += v0; acc += v1; acc += v2; acc += v3;
        }
        for (int j = mfull; j < m; j++) {        // wave-uniform tail (<=3)
            int s = __shfl(sv, j, 64);
            acc += h2[s * HID + lane];
        }
    }
    float v = dn * acc + b2[lane];
    v = fmaxf(v, 0.f);
    v = fminf(v, 10.f);
    xs[wid][lane] = v;                           // comb never hits global
    __syncthreads();

    // ---- Phase B ----
    f32x4 c = ((const f32x4*)xs)[lane];          // lane's 4 comb values
    float* oslot = o_pre + (size_t)(blockIdx.x & (NSLOT - 1)) * 128;

#define COMPG(buf, g) do {                                                                  \
        int j0_ = j0w + (g) * 4;                                                            \
        float a0 = buf[0].x * c.x + buf[0].y * c.y + buf[0].z * c.z + buf[0].w * c.w;       \
        float a1 = buf[1].x * c.x + buf[1].y * c.y + buf[1].z * c.z + buf[1].w * c.w;       \
        float a2 = buf[2].x * c.x + buf[2].y * c.y + buf[2].z * c.z + buf[2].w * c.w;       \
        float a3 = buf[3].x * c.x + buf[3].y * c.y + buf[3].z * c.z + buf[3].w * c.w;       \
        float a0s = a0 + __shfl_xor(a0, 32, 64);                                            \
        float a1s = a1 + __shfl_xor(a1, 32, 64);                                            \
        float a2s = a2 + __shfl_xor(a2, 32, 64);                                            \
        float a3s = a3 + __shfl_xor(a3, 32, 64);                                            \
        float c01 = (lane < 32) ? a0s : a1s;                                                \
        float c23 = (lane < 32) ? a2s : a3s;                                                \
        float c01b = c01 + __shfl_xor(c01, 16, 64);                                         \
        float c23b = c23 + __shfl_xor(c23, 16, 64);                                         \
        float e = ((lane & 16) == 0) ? c01b : c23b;                                         \
        e += __shfl_xor(e, 8, 64);                                                          \
        e += __shfl_xor(e, 4, 64);                                                          \
        e += __shfl_xor(e, 2, 64);                                                          \
        e += __shfl_xor(e, 1, 64);                                                          \
        if ((lane & 15) == 0) {                                                             \
            int roff = ((lane & 16) ? 2 : 0) + ((lane & 32) ? 1 : 0);                       \
            atomicAdd(&oslot[j0_ + roff], e);                                               \
        }                                                                                   \
    } while (0)

    LOADG(bufB, 1); COMPG(bufA, 0);
    LOADG(bufA, 2); COMPG(bufB, 1);
    LOADG(bufB, 3); COMPG(bufA, 2);
    LOADG(bufA, 4); COMPG(bufB, 3);
    LOADG(bufB, 5); COMPG(bufA, 4);
    LOADG(bufA, 6); COMPG(bufB, 5);
    LOADG(bufB, 7); COMPG(bufA, 6);
    COMPG(bufB, 7);
#undef LOADG
#undef COMPG
}

// ---- of2 matvec with fused slot-reduce + relu(o_pre + of1_b + wtail) ----
__global__ __launch_bounds__(256) void k_of2(const float* __restrict__ W, const float* __restrict__ of2b,
                                             const float* __restrict__ o_pre, const float* __restrict__ of1b,
                                             const float* __restrict__ wtail, float* __restrict__ out) {
    __shared__ float os[128];
    int t = threadIdx.x;
    if (t < 128) {
        float s = of1b[t] + wtail[t];
#pragma unroll
        for (int cidx = 0; cidx < NSLOT; cidx++) s += o_pre[cidx * 128 + t];
        os[t] = fmaxf(s, 0.f);
    }
    __syncthreads();
    int k = blockIdx.x * 256 + t;
    if (k >= OUT_DIM) return;
    const f32x4* Wr = (const f32x4*)(W + (size_t)k * 128);
    float acc = of2b[k];
#pragma unroll
    for (int i = 0; i < 32; i++) {
        f32x4 wv = __builtin_nontemporal_load(&Wr[i]);
        int base = i * 4;
        acc += wv.x * os[base + 0] + wv.y * os[base + 1] + wv.z * os[base + 2] + wv.w * os[base + 3];
    }
    out[k] = acc;
}

extern "C" void kernel_launch(void* const* d_in, const int* in_sizes, int n_in,
                              void* d_out, int out_size, void* d_ws, size_t ws_size,
                              hipStream_t stream) {
    const float* x    = (const float*)d_in[0];
    const int*  eidx  = (const int*)d_in[1];
    const float* rain = (const float*)d_in[2];
    const float* fut  = (const float*)d_in[3];
    const float* W1   = (const float*)d_in[4];
    const float* b1   = (const float*)d_in[5];
    const float* W2   = (const float*)d_in[6];
    const float* b2   = (const float*)d_in[7];
    const float* wf1W = (const float*)d_in[8];
    const float* wf1b = (const float*)d_in[9];
    const float* wf2W = (const float*)d_in[10];
    const float* wf2b = (const float*)d_in[11];
    const float* of1W = (const float*)d_in[12];
    const float* of1b = (const float*)d_in[13];
    const float* of2W = (const float*)d_in[14];
    const float* of2b = (const float*)d_in[15];
    float* out = (float*)d_out;

    char* p = (char*)d_ws;
    // zero region: [cursor | o_pre(64 slots x 128)] contiguous -> one memset of 72768 B
    int*   cursor = (int*)(p + 0);            // 10000 ints (= degree after fill)
    float* o_pre  = (float*)(p + 40000);      // 64*128 f32 = 32768 B (ends 72768)
    int*   csr    = (int*)(p + 73728);        // 10000*128 ints = 5.12 MB (ends 5193728)
    float* hlin   = (float*)(p + 5242880);    // 10000*64 f32 (lin1 out, unscaled)
    float* h2     = (float*)(p + 7864320);    // 10000*64 f32 (lin2 out, PRE-SCALED by dinv)
    float* wtail  = (float*)(p + 10485760);   // 128 f32

    hipMemsetAsync(p, 0, 72768, stream);

    k_fill_lin1_weather<<<FILLB + LIN1B + 1, 256, 0, stream>>>(
        eidx, cursor, csr, x, W1, hlin, rain, fut, wf1W, wf1b, wf2W, wf2b, of1W, wtail);

    k_agg1_lin2<<<N_NODES / 4, 256, 0, stream>>>(hlin, cursor, csr, b1, W2, h2);
    k_agg2_of1<<<N_NODES / 4, 256, 0, stream>>>(h2, cursor, csr, b2, of1W, o_pre);

    k_of2<<<(OUT_DIM + 255) / 256, 256, 0, stream>>>(of2W, of2b, o_pre, of1b, wtail, out);
}